// Round 7
// baseline (258.230 us; speedup 1.0000x reference)
//
#include <hip/hip_runtime.h>

// Problem constants (fixed by setup_inputs): N=64, L=256, C=384.
#define N_B    64
#define L_IN   256
#define C_DIM  384
#define C4     (C_DIM / 4)      // 96 float4 per row
#define F4_PER_BLOCK 4096       // 16 iterations x 256 threads, 64 KB stored/block
#define ITERS  (F4_PER_BLOCK / 256)
#define SPLIT  4                // t-range partitions in the idx kernel

// clang-native 4-float vector — accepted by __builtin_nontemporal_store.
typedef float vfloat4 __attribute__((ext_vector_type(4)));

// Kernel 1 (tiny, ~4 us): per-batch cumsum + searchsorted -> r table in ws,
// plus melpos. 64 batches x SPLIT partitions = 256 blocks.
__global__ __launch_bounds__(256) void lr_idx_kernel(const int* __restrict__ dur,
                                                     int* __restrict__ idx_out,
                                                     float* __restrict__ melpos,
                                                     int melmax) {
    __shared__ int csum[L_IN];
    const int n    = blockIdx.x & 63;
    const int part = blockIdx.x >> 6;
    const int tid  = (int)threadIdx.x;

    csum[tid] = dur[n * L_IN + tid];
    __syncthreads();
    #pragma unroll
    for (int off = 1; off < L_IN; off <<= 1) {
        int add = (tid >= off) ? csum[tid - off] : 0;
        __syncthreads();
        csum[tid] += add;
        __syncthreads();
    }
    const int total = csum[L_IN - 1];

    const int per  = (melmax + SPLIT - 1) / SPLIT;
    const int tbeg = part * per;
    const int tend = min(tbeg + per, melmax);
    for (int t = tbeg + tid; t < tend; t += 256) {
        int r = -1;
        if (t < total) {
            int lo = 0, hi = L_IN;
            #pragma unroll
            for (int s = 0; s < 8; ++s) {   // log2(256)
                int mid = (lo + hi) >> 1;
                if (csum[mid] <= t) lo = mid + 1; else hi = mid;
            }
            r = (lo < (L_IN - 1)) ? lo : (L_IN - 1);
        }
        idx_out[n * melmax + t] = r;
        if (n == 0) melpos[t] = (float)(t + 1);   // mel_pos = arange(1, melmax+1)
    }
}

// Kernel 2 (stream): no LDS, no barrier. Each thread loads its 16 idx values
// directly (L2-hot 602 KB table, wave-broadcast addresses), then 16 x loads,
// then 16 non-temporal stores. Chunk-major within an XCD: XCD k streams batch
// k, then k+8, ... so its live x working set (~384 KB) stays L2-resident
// under the write stream.
__global__ __launch_bounds__(256) void lr_gather_kernel(const vfloat4* __restrict__ x,
                                                        const int* __restrict__ idx,
                                                        vfloat4* __restrict__ out,
                                                        int melmax, int chunks_per_n) {
    const int j      = (int)blockIdx.x;
    const int xcd    = j & 7;               // dispatch round-robins XCDs
    const int s      = j >> 3;
    const int n      = xcd + 8 * (s / chunks_per_n);
    const int bchunk = s % chunks_per_n;
    const int tid    = (int)threadIdx.x;

    const int row_f4 = melmax * C4;
    const int start  = bchunk * F4_PER_BLOCK;
    if (start >= row_f4) return;
    const bool full  = (start + F4_PER_BLOCK) <= row_f4;
    const int end    = full ? (start + F4_PER_BLOCK) : row_f4;

    const int ibase = n * melmax;
    const size_t obase = (size_t)n * row_f4;

    if (full) {
        int r[ITERS];
        #pragma unroll
        for (int i = 0; i < ITERS; ++i) {
            const int off = start + tid + 256 * i;
            const int t   = off / C4;            // const divisor -> mul/shift
            r[i] = idx[ibase + t];
        }
        vfloat4 v[ITERS];
        #pragma unroll
        for (int i = 0; i < ITERS; ++i) {
            const int off = start + tid + 256 * i;
            const int t   = off / C4;
            const int c4  = off - t * C4;
            const int rc  = (r[i] >= 0) ? r[i] : 0;  // unconditional load; select after
            vfloat4 tmp = x[(n * L_IN + rc) * C4 + c4];
            v[i] = (r[i] >= 0) ? tmp : (vfloat4)0.f;
        }
        #pragma unroll
        for (int i = 0; i < ITERS; ++i) {
            __builtin_nontemporal_store(v[i], &out[obase + start + tid + 256 * i]);
        }
    } else {
        for (int off = start + tid; off < end; off += 256) {
            const int t  = off / C4;
            const int c4 = off - t * C4;
            const int r  = idx[ibase + t];
            vfloat4 v = (vfloat4)0.f;
            if (r >= 0) v = x[(n * L_IN + r) * C4 + c4];
            __builtin_nontemporal_store(v, &out[obase + off]);
        }
    }
}

extern "C" void kernel_launch(void* const* d_in, const int* in_sizes, int n_in,
                              void* d_out, int out_size, void* d_ws, size_t ws_size,
                              hipStream_t stream) {
    const float* x  = (const float*)d_in[0];
    const int* dur  = (const int*)d_in[1];
    // d_in[2] (mel_max_length) is device-resident; derive on host:
    // out_size = N*mel*C + mel = mel * (N*C + 1)
    const int melmax = out_size / (N_B * C_DIM + 1);

    int* idxbuf = (int*)d_ws;                                   // N_B*melmax ints
    float* mp   = (float*)d_out + (size_t)N_B * melmax * C_DIM; // mel_pos

    lr_idx_kernel<<<N_B * SPLIT, 256, 0, stream>>>(dur, idxbuf, mp, melmax);

    const int row_f4 = melmax * C4;
    const int chunks_per_n = (row_f4 + F4_PER_BLOCK - 1) / F4_PER_BLOCK;
    lr_gather_kernel<<<chunks_per_n * N_B, 256, 0, stream>>>(
        (const vfloat4*)x, idxbuf, (vfloat4*)d_out, melmax, chunks_per_n);
}